// Round 9
// baseline (167.816 us; speedup 1.0000x reference)
//
#include <hip/hip_runtime.h>
#include <math.h>

// InfoNCE loss, K=3, SKIP=1, NEG=64
// z,c: (64,256,14,14) f32; Wk: (3,256,256) f32; neg_idx_k: (rows_k*64,) i32
// rows_k = 10752, 9856, 8960. row = (h*14+w)*64 + b.
//
// Pipeline (4 launches): prep (casts+transposes+zero out), proj (LDS-staged
// bf16 MFMA GEMM -> ztwk fp8, L2-resident), loss (producer/consumer double-
// buffered: wave1 DMAs task t+1's 65 rows+ctx into LDS while wave0 runs fp8
// MFMA + softmax on task t), reduce.

typedef short bf16x8 __attribute__((ext_vector_type(8)));
typedef float f32x4 __attribute__((ext_vector_type(4)));

static __device__ __forceinline__ unsigned short f2bf(float f) {
    union { float f; unsigned int u; } x; x.f = f;
    unsigned int r = x.u + 0x7fffu + ((x.u >> 16) & 1u);   // RNE
    return (unsigned short)(r >> 16);
}

// float -> OCP e4m3fn (RNE, saturate to 448, subnormals handled)
static __device__ __forceinline__ unsigned char f2e4m3(float f) {
    union { float f; unsigned int u; } x; x.f = f;
    unsigned int s = (x.u >> 24) & 0x80u;
    float af = fabsf(f);
    if (af > 448.f) af = 448.f;
    x.f = af;
    unsigned int u = x.u;
    int e = (int)(u >> 23) - 127;
    unsigned int out;
    if (af == 0.f) {
        out = 0u;
    } else if (e < -6) {
        int mq = (int)rintf(af * 512.f);          // multiples of 2^-9
        out = (mq >= 8) ? 0x08u : (unsigned int)mq;
    } else {
        unsigned int r = u + 0x7FFFFu + ((u >> 20) & 1u);  // RNE, drop 20 bits
        int e2 = (int)(r >> 23) - 127;
        if (e2 > 8) out = 0x7Eu;                  // 448
        else out = (unsigned int)(((e2 + 7) << 3) | ((r >> 20) & 7u));
    }
    return (unsigned char)(s | out);
}

// async global->LDS DMA: per-lane global addr, dest = uniform base + lane*4
static __device__ __forceinline__ void gload_lds4(const void* g, void* l) {
    __builtin_amdgcn_global_load_lds(
        (const __attribute__((address_space(1))) void*)g,
        (__attribute__((address_space(3))) void*)l, 4, 0, 0);
}

// prep: blocks [0,768): Wk->bf16 (block0 also zeroes out[0]);
// [768,1792): z -> zt bf16 transposed; [1792,2816): c -> ct8 fp8 transposed.
__global__ __launch_bounds__(256)
void prep_kernel(const float* __restrict__ z, const float* __restrict__ c,
                 const float* __restrict__ Wk,
                 unsigned short* __restrict__ zt, unsigned char* __restrict__ ct8,
                 unsigned short* __restrict__ wkb, float* __restrict__ out) {
    __shared__ float tile[16][201];
    const int tid = threadIdx.x;
    int x = blockIdx.x;
    if (x < 768) {
        int i = x * 256 + tid;
        wkb[i] = f2bf(Wk[i]);
        if (x == 0 && tid == 0) out[0] = 0.f;
        return;
    }
    const bool isz = x < 1792;
    const int local = isz ? (x - 768) : (x - 1792);
    const float* src = isz ? z : c;
    const int b  = local & 63;
    const int c0 = (local >> 6) << 4;
    for (int i = tid; i < 16 * 196; i += 256) {
        int cc = i / 196;
        int hw = i - cc * 196;
        tile[cc][hw] = src[(size_t)((b << 8) + c0 + cc) * 196 + hw];
    }
    __syncthreads();
    if (isz) {
        for (int i = tid; i < 196 * 16; i += 256) {
            int hw = i >> 4, cc = i & 15;
            zt[(size_t)((hw << 6) + b) * 256 + c0 + cc] = f2bf(tile[cc][hw]);
        }
    } else {
        for (int i = tid; i < 196 * 16; i += 256) {
            int hw = i >> 4, cc = i & 15;
            ct8[(size_t)((hw << 6) + b) * 256 + c0 + cc] = f2e4m3(tile[cc][hw]);
        }
    }
}

// proj: ztwk8[k][row][o] = fp8(sum_c zt[zrow][c] * wk[k][o][c])
// Tile M=64 x N=32, grid (462, 8). Coalesced b128 stage into padded LDS
// (row stride 544 B), frags from LDS, fp8 epilogue via LDS. (Verified R8.)
#define PSTR 544
__global__ __launch_bounds__(256)
void proj_mfma_kernel(const unsigned short* __restrict__ zt,
                      const unsigned short* __restrict__ wkb,
                      unsigned char* __restrict__ ztwk) {
    __shared__ __align__(16) unsigned char smem[(64 + 32) * PSTR];  // 52224 B
    unsigned char* smA = smem;
    unsigned char* smB = smem + 64 * PSTR;

    int x = blockIdx.x;
    int k, hw;
    if (x < 168)      { k = 0; hw = x; }
    else if (x < 322) { k = 1; hw = x - 168; }
    else              { k = 2; hw = x - 322; }
    const int o0 = blockIdx.y << 5;
    const int row0  = hw << 6;
    const int zrow0 = row0 + (((k + 2) * 14) << 6);    // h' = h + (k_idx+2)
    unsigned char* zo = ztwk + (size_t)k * 10752 * 256;

    const int tid = threadIdx.x;
    const unsigned char* zsrc = (const unsigned char*)(zt + (size_t)zrow0 * 256);
    const unsigned char* bsrc = (const unsigned char*)(wkb + ((size_t)k << 16) + o0 * 256);

    #pragma unroll
    for (int i = 0; i < 8; ++i) {          // A: 32 KB contiguous
        int sb = ((i << 8) + tid) << 4;
        int r = sb >> 9, off = sb & 511;
        *(int4*)(smA + r * PSTR + off) = *(const int4*)(zsrc + sb);
    }
    #pragma unroll
    for (int i = 0; i < 4; ++i) {          // B: 16 KB contiguous
        int sb = ((i << 8) + tid) << 4;
        int r = sb >> 9, off = sb & 511;
        *(int4*)(smB + r * PSTR + off) = *(const int4*)(bsrc + sb);
    }
    __syncthreads();

    const int wv = tid >> 6, lane = tid & 63;
    const int m = lane & 15, kq = lane >> 4;
    f32x4 acc[2] = {};
    const unsigned short* aP  = (const unsigned short*)(smA + (size_t)((wv << 4) + m) * PSTR) + (kq << 3);
    const unsigned short* bP0 = (const unsigned short*)(smB + (size_t)m * PSTR) + (kq << 3);
    const unsigned short* bP1 = (const unsigned short*)(smB + (size_t)(16 + m) * PSTR) + (kq << 3);
    #pragma unroll
    for (int kk = 0; kk < 256; kk += 32) {
        bf16x8 af = *(const bf16x8*)(aP  + kk);
        bf16x8 b0 = *(const bf16x8*)(bP0 + kk);
        bf16x8 b1 = *(const bf16x8*)(bP1 + kk);
        acc[0] = __builtin_amdgcn_mfma_f32_16x16x32_bf16(af, b0, acc[0], 0, 0, 0);
        acc[1] = __builtin_amdgcn_mfma_f32_16x16x32_bf16(af, b1, acc[1], 0, 0, 0);
    }
    __syncthreads();
    unsigned char* cs = smA;               // [64 rows][40 B]
    #pragma unroll
    for (int nt = 0; nt < 2; ++nt)
        #pragma unroll
        for (int r = 0; r < 4; ++r)
            cs[(size_t)((wv << 4) + (kq << 2) + r) * 40 + (nt << 4) + m] =
                f2e4m3(acc[nt][r]);
    __syncthreads();
    {
        int r = tid >> 2, off = (tid & 3) << 3;
        unsigned long long v = *(const unsigned long long*)(cs + (size_t)r * 40 + off);
        *(unsigned long long*)(zo + (size_t)(row0 + r) * 256 + o0 + off) = v;
    }
}

// loss: 1848 blocks x 128 thr; block handles TPB=16 consecutive rows of one
// k-segment (segments all divisible by 16). Wave1 = producer: DMA-gathers
// task t+1's 65 rows + ctx into slab[(t+1)&1] (idx prefetched one task
// deeper). Wave0 = consumer: fp8 MFMA (5 M-tiles, slot-64 clamp for pads)
// + full softmax from slab[t&1]. One barrier per task; its vmcnt drain is
// covered by consumer compute.
#define ROWB 272
#define TPB 16
__global__ __launch_bounds__(128, 2)
void loss_mfma_kernel(const unsigned char* __restrict__ ct8,
                      const unsigned char* __restrict__ ztwk8,
                      const int* __restrict__ n0, const int* __restrict__ n1,
                      const int* __restrict__ n2, float* __restrict__ rowloss) {
    __shared__ __align__(16) unsigned char slab[2][65 * ROWB];   // 35360 B
    __shared__ __align__(16) unsigned char ctx_s[2][256];
    const int tid = threadIdx.x;
    const int wv = tid >> 6, lane = tid & 63;
    const int m = lane & 15, kq = lane >> 4;

    const int task0 = blockIdx.x * TPB;
    int k; const int* nb; int segbase;
    if (task0 < 10752)      { k = 0; nb = n0; segbase = 0; }
    else if (task0 < 20608) { k = 1; nb = n1; segbase = 10752; }
    else                    { k = 2; nb = n2; segbase = 20608; }
    const int row0 = task0 - segbase;
    const unsigned char* flat8 = ztwk8 + (size_t)k * 10752 * 256;
    const float wkf = (k == 0) ? (1.f / (3.f * 10752.f))
                    : (k == 1) ? (1.f / (3.f * 9856.f))
                               : (1.f / (3.f * 8960.f));

    int myidx_next = 0;
    if (wv == 1) {
        // prologue: gather task 0 into buffer 0
        int idx0 = nb[((size_t)row0 << 6) + lane];
        gload_lds4(flat8 + (size_t)row0 * 256 + (lane << 2), &slab[0][0]);
        gload_lds4(ct8 + (size_t)row0 * 256 + (lane << 2), &ctx_s[0][0]);
        #pragma unroll
        for (int j = 1; j <= 64; ++j) {
            int idx = __builtin_amdgcn_readlane(idx0, j - 1);
            gload_lds4(flat8 + (size_t)idx * 256 + (lane << 2), &slab[0][j * ROWB]);
        }
        myidx_next = nb[((size_t)(row0 + 1) << 6) + lane];
    }
    __syncthreads();

    int soff[5];
    #pragma unroll
    for (int mt = 0; mt < 5; ++mt) {
        int slot = (mt << 4) + m;
        if (slot > 64) slot = 64;           // pad slots duplicate 64 (excluded)
        soff[mt] = slot * ROWB + (kq << 3);
    }

    for (int t = 0; t < TPB; ++t) {
        const int buf = t & 1;
        if (wv == 1) {
            if (t + 1 < TPB) {
                const int rn = row0 + t + 1;
                const int nbuf = buf ^ 1;
                gload_lds4(flat8 + (size_t)rn * 256 + (lane << 2), &slab[nbuf][0]);
                gload_lds4(ct8 + (size_t)rn * 256 + (lane << 2), &ctx_s[nbuf][0]);
                #pragma unroll
                for (int j = 1; j <= 64; ++j) {
                    int idx = __builtin_amdgcn_readlane(myidx_next, j - 1);
                    gload_lds4(flat8 + (size_t)idx * 256 + (lane << 2),
                               &slab[nbuf][j * ROWB]);
                }
                if (t + 2 < TPB)
                    myidx_next = nb[((size_t)(row0 + t + 2) << 6) + lane];
            }
        } else {
            f32x4 acc[5] = {};
            const unsigned char* sl = &slab[buf][0];
            const unsigned char* cp = &ctx_s[buf][kq << 3];
            #pragma unroll
            for (int kk = 0; kk < 8; ++kk) {
                long long bfrag = *(const long long*)(cp + (kk << 5));
                #pragma unroll
                for (int mt = 0; mt < 5; ++mt) {
                    long long af = *(const long long*)(sl + soff[mt] + (kk << 5));
                    acc[mt] = __builtin_amdgcn_mfma_f32_16x16x32_fp8_fp8(
                        af, bfrag, acc[mt], 0, 0, 0);
                }
            }
            // softmax over slots 0..64 (slot = mt*16 + kq*4 + r)
            float m_l = -1e30f;
            #pragma unroll
            for (int mt = 0; mt < 4; ++mt)
                #pragma unroll
                for (int r = 0; r < 4; ++r) m_l = fmaxf(m_l, acc[mt][r]);
            if (kq == 0) m_l = fmaxf(m_l, acc[4][0]);
            m_l = fmaxf(m_l, __shfl_xor(m_l, 16));
            m_l = fmaxf(m_l, __shfl_xor(m_l, 32));
            float s_l = 0.f;
            #pragma unroll
            for (int mt = 0; mt < 4; ++mt)
                #pragma unroll
                for (int r = 0; r < 4; ++r) s_l += __expf(acc[mt][r] - m_l);
            if (kq == 0) s_l += __expf(acc[4][0] - m_l);
            s_l += __shfl_xor(s_l, 16);
            s_l += __shfl_xor(s_l, 32);
            if (lane == 0) {               // lane 0 holds slot 0 (acc[0][0])
                float p0 = __expf(acc[0][0] - m_l) / s_l;
                rowloss[segbase + row0 + t] = -logf(p0 + 1e-11f) * wkf;
            }
        }
        __syncthreads();
    }
}

// Sum rowloss[0..29568) -> out[0] (out zeroed in prep)
__global__ __launch_bounds__(256)
void reduce_kernel(const float* __restrict__ rl, float* __restrict__ out) {
    float s = 0.f;
    const int stride = gridDim.x * blockDim.x;
    for (int i = blockIdx.x * blockDim.x + threadIdx.x; i < 29568; i += stride)
        s += rl[i];
    #pragma unroll
    for (int off = 32; off >= 1; off >>= 1) s += __shfl_xor(s, off);
    if ((threadIdx.x & 63) == 0) atomicAdd(out, s);
}

extern "C" void kernel_launch(void* const* d_in, const int* in_sizes, int n_in,
                              void* d_out, int out_size, void* d_ws, size_t ws_size,
                              hipStream_t stream) {
    const float* z  = (const float*)d_in[0];
    const float* c  = (const float*)d_in[1];
    const float* Wk = (const float*)d_in[2];
    const int* negs[3] = {(const int*)d_in[3], (const int*)d_in[4], (const int*)d_in[5]};
    float* out = (float*)d_out;

    // workspace: zt bf16 6.4MB | wkb bf16 384KB | ct8 fp8 3.2MB |
    // ztwk8 fp8 [3][10752][256] 8.26MB | rowloss f32 118KB
    char* p = (char*)d_ws;
    unsigned short* zt      = (unsigned short*)p;   p += (size_t)196 * 64 * 256 * 2;
    unsigned short* wkb     = (unsigned short*)p;   p += (size_t)3 * 65536 * 2;
    unsigned char*  ct8     = (unsigned char*)p;    p += (size_t)196 * 64 * 256;
    unsigned char*  ztwk8   = (unsigned char*)p;    p += (size_t)3 * 10752 * 256;
    float*          rowloss = (float*)p;

    prep_kernel<<<2816, 256, 0, stream>>>(z, c, Wk, zt, ct8, wkb, out);
    proj_mfma_kernel<<<dim3(462, 8), 256, 0, stream>>>(zt, wkb, ztwk8);
    loss_mfma_kernel<<<1848, 128, 0, stream>>>(ct8, ztwk8, negs[0], negs[1],
                                               negs[2], rowloss);
    reduce_kernel<<<32, 256, 0, stream>>>(rowloss, out);
}